// Round 4
// baseline (491.553 us; speedup 1.0000x reference)
//
#include <hip/hip_runtime.h>
#include <stdint.h>

// ---------------------------------------------------------------------------
// RLMALinear: out = x @ (alpha*R + U@V)^T + bias
//   x: [32,4096,512] f32, U: [512,64] f32, V: [64,512] f32, bias: [512] f32
// Stage 1: build W (bf16) in d_ws via threefry2x32 + erfinv.
// Stage 2: W-STATIONARY GEMM. Block stages its 128x512 W panel into LDS once
//   (133 KB), then streams x global->reg->cvt->MFMA, zero main-loop barriers.
//   R3 fix: PF=4 so PF | NSTEP -- prefetch slot phase is tile-invariant
//   (PF=3 corrupted tiles 1..7: 16 mod 3 != 0). hipFuncSetAttribute now
//   unconditional (no static guard).
// ---------------------------------------------------------------------------

#define M_TOTAL 131072
#define N_DIM 512
#define K_DIM 512
#define RANK 64

#define BN_BLK 128        // W-panel rows (output cols) per block
#define BM_TILE 128       // rows per m-tile (2 m-waves x 4 frags x 16)
#define MT_PER_BLK 8      // m-tiles per block
#define LDW 520           // padded shorts per W row: 1040B stride == 1 quad
                          // mod 8 -> uniform bank-quad spread on b128 reads
#define NSTEP 16          // K steps of 32
#define PF 4              // prefetch depth; MUST divide NSTEP

typedef __attribute__((ext_vector_type(8))) short bf16x8;
typedef __attribute__((ext_vector_type(4))) float f32x4;

// ---- JAX threefry2x32 -----------------------------------------------------
__device__ __forceinline__ void threefry2x32(uint32_t k0, uint32_t k1,
                                             uint32_t x0, uint32_t x1,
                                             uint32_t& y0, uint32_t& y1) {
  uint32_t ks2 = k0 ^ k1 ^ 0x1BD11BDAu;
  const uint32_t ks[3] = {k0, k1, ks2};
  const int R0[4] = {13, 15, 26, 6};
  const int R1[4] = {17, 29, 16, 24};
  x0 += ks[0];
  x1 += ks[1];
#pragma unroll
  for (int g = 0; g < 5; ++g) {
    const int* r = (g & 1) ? R1 : R0;
#pragma unroll
    for (int i = 0; i < 4; ++i) {
      x0 += x1;
      x1 = (x1 << r[i]) | (x1 >> (32 - r[i]));
      x1 ^= x0;
    }
    x0 += ks[(g + 1) % 3];
    x1 += ks[(g + 2) % 3] + (uint32_t)(g + 1);
  }
  y0 = x0;
  y1 = x1;
}

// ---- XLA ErfInv32 (Giles 2012) --------------------------------------------
__device__ __forceinline__ float erfinv_f32(float x) {
  float w = -log1pf(-x * x);
  float p;
  if (w < 5.0f) {
    w = w - 2.5f;
    p = 2.81022636e-08f;
    p = fmaf(p, w, 3.43273939e-07f);
    p = fmaf(p, w, -3.5233877e-06f);
    p = fmaf(p, w, -4.39150654e-06f);
    p = fmaf(p, w, 0.00021858087f);
    p = fmaf(p, w, -0.00125372503f);
    p = fmaf(p, w, -0.00417768164f);
    p = fmaf(p, w, 0.246640727f);
    p = fmaf(p, w, 1.50140941f);
  } else {
    w = sqrtf(w) - 3.0f;
    p = -0.000200214257f;
    p = fmaf(p, w, 0.000100950558f);
    p = fmaf(p, w, 0.00134934322f);
    p = fmaf(p, w, -0.00367342844f);
    p = fmaf(p, w, 0.00573950773f);
    p = fmaf(p, w, -0.0076224613f);
    p = fmaf(p, w, 0.00943887047f);
    p = fmaf(p, w, 1.00167406f);
    p = fmaf(p, w, 2.83297682f);
  }
  return p * x;
}

__device__ __forceinline__ unsigned short f32_to_bf16_rtne(float f) {
  uint32_t x = __float_as_uint(f);
  uint32_t r = (x + 0x7FFFu + ((x >> 16) & 1u)) >> 16;
  return (unsigned short)r;
}

// ---- Stage 1 --------------------------------------------------------------
__global__ __launch_bounds__(256) void build_w_kernel(
    const float* __restrict__ alpha_p, const float* __restrict__ U,
    const float* __restrict__ V, const int* __restrict__ k_iter_p,
    unsigned short* __restrict__ Wb) {
  int idx = blockIdx.x * blockDim.x + threadIdx.x;
  uint32_t s = (1234u ^ (uint32_t)(*k_iter_p));
  uint32_t y0, y1;
  threefry2x32(0u, s, 0u, (uint32_t)idx, y0, y1);
  uint32_t bits = y0 ^ y1;
  float u01 = __uint_as_float((bits >> 9) | 0x3f800000u) - 1.0f;
  const float lo = -0.99999994f;
  float u = fmaxf(lo, u01 * 2.0f + lo);
  float rnorm = 1.41421354f * erfinv_f32(u);
  const float scale = 0.044194173824159216f;  // fp32(1/sqrt(512))

  int o = idx >> 9;
  int i = idx & 511;
  float uv = 0.0f;
#pragma unroll 8
  for (int r = 0; r < RANK; ++r)
    uv = fmaf(U[o * RANK + r], V[r * N_DIM + i], uv);

  float w = (*alpha_p) * (rnorm * scale) + uv;
  Wb[idx] = f32_to_bf16_rtne(w);
}

// ---- Stage 2: W-stationary GEMM ------------------------------------------
__device__ __forceinline__ bf16x8 cvt8(const float4& lo, const float4& hi) {
  union {
    bf16x8 v;
    uint32_t d[4];
  } au;
  asm("v_cvt_pk_bf16_f32 %0, %1, %2" : "=v"(au.d[0]) : "v"(lo.x), "v"(lo.y));
  asm("v_cvt_pk_bf16_f32 %0, %1, %2" : "=v"(au.d[1]) : "v"(lo.z), "v"(lo.w));
  asm("v_cvt_pk_bf16_f32 %0, %1, %2" : "=v"(au.d[2]) : "v"(hi.x), "v"(hi.y));
  asm("v_cvt_pk_bf16_f32 %0, %1, %2" : "=v"(au.d[3]) : "v"(hi.z), "v"(hi.w));
  return au.v;
}

__global__ __launch_bounds__(512, 2) void gemm_kernel(
    const float* __restrict__ X, const unsigned short* __restrict__ Wb,
    const float* __restrict__ bias, float* __restrict__ Out) {
  extern __shared__ unsigned short Ws[];  // [128][LDW]

  const int tid = threadIdx.x;
  // grid 512 = 8 XCD x 64. XCD x gets l in [64x, 64x+64): the 4 nb-sharers of
  // each m-group are on the SAME XCD, nearly simultaneous -> L2 shares x.
  const int p = blockIdx.x;
  const int l = (p & 7) * 64 + (p >> 3);
  const int nb = l & 3;        // n quarter (128 cols)
  const int mg = l >> 2;       // 0..127 -> m base
  const int n0 = nb * BN_BLK;
  const size_t blk_m = (size_t)mg * (BM_TILE * MT_PER_BLK);

  // ---- stage W panel once: rows n0..n0+127, all K, padded rows ----
#pragma unroll
  for (int it = 0; it < 16; ++it) {
    int u = it * 512 + tid;    // 8192 units of 16B
    int row = u >> 6;
    int c = u & 63;
    bf16x8 v = *reinterpret_cast<const bf16x8*>(
        &Wb[(size_t)(n0 + row) * K_DIM + c * 8]);
    *reinterpret_cast<bf16x8*>(&Ws[row * LDW + c * 8]) = v;
  }
  __syncthreads();  // the only barrier in this kernel

  const int lane = tid & 63;
  const int wave = tid >> 6;   // 8 waves: 2m x 4n
  const int wm = wave >> 2;    // 0..1 -> 64 rows each
  const int wn = wave & 3;     // 0..3 -> 32 cols each
  const int r = lane & 15;
  const int g = lane >> 4;

  // per-thread x base: row = blk_m + wm*64 + r (+i*16 per frag), col g*8
  const float* xbase = X + (blk_m + wm * 64 + r) * K_DIM + g * 8;
  // per-thread W LDS base (ushort idx): row = wn*32 + r (+jj*16), col g*8
  const int wsbase = (wn * 32 + r) * LDW + g * 8;

  float bv[2];
#pragma unroll
  for (int jj = 0; jj < 2; ++jj)
    bv[jj] = bias[n0 + wn * 32 + jj * 16 + r];

  // prefetch slots: [PF][frag i][half]; PF | NSTEP -> phase tile-invariant
  float4 xq[PF][4][2];

  const float* xm = xbase;
  // prologue: fill pipeline for tile 0, steps 0..PF-1
#pragma unroll
  for (int s = 0; s < PF; ++s)
#pragma unroll
    for (int i = 0; i < 4; ++i) {
      xq[s][i][0] = *reinterpret_cast<const float4*>(xm + (size_t)i * 16 * K_DIM + s * 32);
      xq[s][i][1] = *reinterpret_cast<const float4*>(xm + (size_t)i * 16 * K_DIM + s * 32 + 4);
    }

  for (int mt = 0; mt < MT_PER_BLK; ++mt) {
    f32x4 acc[4][2];
#pragma unroll
    for (int i = 0; i < 4; ++i)
#pragma unroll
      for (int jj = 0; jj < 2; ++jj) acc[i][jj] = (f32x4){0.f, 0.f, 0.f, 0.f};

#pragma unroll
    for (int s = 0; s < NSTEP; ++s) {
      const int slot = s % PF;
      // consume slot -> bf16 a-frags
      bf16x8 a[4];
#pragma unroll
      for (int i = 0; i < 4; ++i) a[i] = cvt8(xq[slot][i][0], xq[slot][i][1]);

      // refill slot with step s+PF (same tile) or next tile's step s+PF-NSTEP
      if (s < NSTEP - PF) {
#pragma unroll
        for (int i = 0; i < 4; ++i) {
          xq[slot][i][0] = *reinterpret_cast<const float4*>(
              xm + (size_t)i * 16 * K_DIM + (s + PF) * 32);
          xq[slot][i][1] = *reinterpret_cast<const float4*>(
              xm + (size_t)i * 16 * K_DIM + (s + PF) * 32 + 4);
        }
      } else if (mt < MT_PER_BLK - 1) {
        const float* xn = xm + (size_t)BM_TILE * K_DIM;
#pragma unroll
        for (int i = 0; i < 4; ++i) {
          xq[slot][i][0] = *reinterpret_cast<const float4*>(
              xn + (size_t)i * 16 * K_DIM + (s + PF - NSTEP) * 32);
          xq[slot][i][1] = *reinterpret_cast<const float4*>(
              xn + (size_t)i * 16 * K_DIM + (s + PF - NSTEP) * 32 + 4);
        }
      }

      // b-frags from LDS + MFMA
#pragma unroll
      for (int jj = 0; jj < 2; ++jj) {
        bf16x8 b = *reinterpret_cast<const bf16x8*>(
            &Ws[wsbase + jj * 16 * LDW + s * 32]);
#pragma unroll
        for (int i = 0; i < 4; ++i)
          acc[i][jj] = __builtin_amdgcn_mfma_f32_16x16x32_bf16(a[i], b,
                                                               acc[i][jj], 0, 0, 0);
      }
    }

    // epilogue for this m-tile (C map: col=lane&15, row=(lane>>4)*4+q)
    const size_t mrow0 = blk_m + (size_t)mt * BM_TILE + wm * 64 + (lane >> 4) * 4;
#pragma unroll
    for (int jj = 0; jj < 2; ++jj) {
      const int oc = n0 + wn * 32 + jj * 16 + r;
#pragma unroll
      for (int i = 0; i < 4; ++i) {
        const size_t rb = mrow0 + i * 16;
#pragma unroll
        for (int q = 0; q < 4; ++q)
          Out[(rb + q) * N_DIM + oc] = acc[i][jj][q] + bv[jj];
      }
    }

    xm += (size_t)BM_TILE * K_DIM;
  }
}

extern "C" void kernel_launch(void* const* d_in, const int* in_sizes, int n_in,
                              void* d_out, int out_size, void* d_ws,
                              size_t ws_size, hipStream_t stream) {
  (void)in_sizes;
  (void)n_in;
  (void)out_size;
  (void)ws_size;
  const float* x = (const float*)d_in[0];
  const float* alpha = (const float*)d_in[1];
  const float* U = (const float*)d_in[2];
  const float* V = (const float*)d_in[3];
  const float* bias = (const float*)d_in[4];
  const int* k_iter = (const int*)d_in[5];
  float* out = (float*)d_out;
  unsigned short* Wb = (unsigned short*)d_ws;  // 512 KiB scratch

  build_w_kernel<<<(N_DIM * K_DIM) / 256, 256, 0, stream>>>(alpha, U, V,
                                                            k_iter, Wb);

  const int lds_bytes = BN_BLK * LDW * 2;  // 133,120 B
  hipFuncSetAttribute((const void*)gemm_kernel,
                      hipFuncAttributeMaxDynamicSharedMemorySize, lds_bytes);
  const int grid = 4 * (M_TOTAL / (BM_TILE * MT_PER_BLK));  // 4 x 128 = 512
  gemm_kernel<<<grid, 512, lds_bytes, stream>>>(x, Wb, bias, out);
}

// Round 6
// 167.114 us; speedup vs baseline: 2.9414x; 2.9414x over previous
//
#include <hip/hip_runtime.h>
#include <stdint.h>

// ---------------------------------------------------------------------------
// RLMALinear: out = x @ (alpha*R + U@V)^T + bias
//   x: [32,4096,512] f32, U: [512,64] f32, V: [64,512] f32, bias: [512] f32
// Stage 1: build W (bf16) in d_ws via threefry2x32 + erfinv.
// Stage 2: block = 128 m-rows x ALL 512 n-cols, K-tiled by 32.
//   x staged f32 + W staged bf16 via global_load_lds (zero VGPR cost),
//   both double-buffered, ONE barrier per K-step. Both-sides 16B-granule
//   XOR swizzle on LDS. acc[4][8] f32x4 = 128 VGPR, statically indexed.
//   x is read from HBM exactly once (no n-redundancy).
// R5 fix: ADVANCE stepped pW by 128 B/K-step; a 32-bf16 K-step is 64 B.
//   (A: 32 f32 = 128 B was correct.) W slices were misaligned from step 1 on.
// ---------------------------------------------------------------------------

#define M_TOTAL 131072
#define N_DIM 512
#define K_DIM 512
#define RANK 64

#define BM 128
#define BK 32
#define NKT (K_DIM / BK)  // 16

// LDS layout (bytes): A0 @ 0, A1 @ 16384, W0 @ 32768, W1 @ 65536. Total 98304.
#define AOFF(p) ((p)*16384)
#define WOFF(p) (32768 + (p)*32768)

typedef __attribute__((ext_vector_type(8))) short bf16x8;
typedef __attribute__((ext_vector_type(4))) float f32x4;

// ---- JAX threefry2x32 -----------------------------------------------------
__device__ __forceinline__ void threefry2x32(uint32_t k0, uint32_t k1,
                                             uint32_t x0, uint32_t x1,
                                             uint32_t& y0, uint32_t& y1) {
  uint32_t ks2 = k0 ^ k1 ^ 0x1BD11BDAu;
  const uint32_t ks[3] = {k0, k1, ks2};
  const int R0[4] = {13, 15, 26, 6};
  const int R1[4] = {17, 29, 16, 24};
  x0 += ks[0];
  x1 += ks[1];
#pragma unroll
  for (int g = 0; g < 5; ++g) {
    const int* r = (g & 1) ? R1 : R0;
#pragma unroll
    for (int i = 0; i < 4; ++i) {
      x0 += x1;
      x1 = (x1 << r[i]) | (x1 >> (32 - r[i]));
      x1 ^= x0;
    }
    x0 += ks[(g + 1) % 3];
    x1 += ks[(g + 2) % 3] + (uint32_t)(g + 1);
  }
  y0 = x0;
  y1 = x1;
}

// ---- XLA ErfInv32 (Giles 2012) --------------------------------------------
__device__ __forceinline__ float erfinv_f32(float x) {
  float w = -log1pf(-x * x);
  float p;
  if (w < 5.0f) {
    w = w - 2.5f;
    p = 2.81022636e-08f;
    p = fmaf(p, w, 3.43273939e-07f);
    p = fmaf(p, w, -3.5233877e-06f);
    p = fmaf(p, w, -4.39150654e-06f);
    p = fmaf(p, w, 0.00021858087f);
    p = fmaf(p, w, -0.00125372503f);
    p = fmaf(p, w, -0.00417768164f);
    p = fmaf(p, w, 0.246640727f);
    p = fmaf(p, w, 1.50140941f);
  } else {
    w = sqrtf(w) - 3.0f;
    p = -0.000200214257f;
    p = fmaf(p, w, 0.000100950558f);
    p = fmaf(p, w, 0.00134934322f);
    p = fmaf(p, w, -0.00367342844f);
    p = fmaf(p, w, 0.00573950773f);
    p = fmaf(p, w, -0.0076224613f);
    p = fmaf(p, w, 0.00943887047f);
    p = fmaf(p, w, 1.00167406f);
    p = fmaf(p, w, 2.83297682f);
  }
  return p * x;
}

__device__ __forceinline__ unsigned short f32_to_bf16_rtne(float f) {
  uint32_t x = __float_as_uint(f);
  uint32_t r = (x + 0x7FFFu + ((x >> 16) & 1u)) >> 16;
  return (unsigned short)r;
}

// ---- Stage 1 --------------------------------------------------------------
__global__ __launch_bounds__(256) void build_w_kernel(
    const float* __restrict__ alpha_p, const float* __restrict__ U,
    const float* __restrict__ V, const int* __restrict__ k_iter_p,
    unsigned short* __restrict__ Wb) {
  int idx = blockIdx.x * blockDim.x + threadIdx.x;
  uint32_t s = (1234u ^ (uint32_t)(*k_iter_p));
  uint32_t y0, y1;
  threefry2x32(0u, s, 0u, (uint32_t)idx, y0, y1);
  uint32_t bits = y0 ^ y1;
  float u01 = __uint_as_float((bits >> 9) | 0x3f800000u) - 1.0f;
  const float lo = -0.99999994f;
  float u = fmaxf(lo, u01 * 2.0f + lo);
  float rnorm = 1.41421354f * erfinv_f32(u);
  const float scale = 0.044194173824159216f;  // fp32(1/sqrt(512))

  int o = idx >> 9;
  int i = idx & 511;
  float uv = 0.0f;
#pragma unroll 8
  for (int r = 0; r < RANK; ++r)
    uv = fmaf(U[o * RANK + r], V[r * N_DIM + i], uv);

  float w = (*alpha_p) * (rnorm * scale) + uv;
  Wb[idx] = f32_to_bf16_rtne(w);
}

// ---- async 16B global->LDS ------------------------------------------------
__device__ __forceinline__ void gload16(const void* g, void* l) {
  __builtin_amdgcn_global_load_lds(
      (const __attribute__((address_space(1))) void*)g,
      (__attribute__((address_space(3))) void*)l, 16, 0, 0);
}

__device__ __forceinline__ bf16x8 cvt8(const float4& lo, const float4& hi) {
  union {
    bf16x8 v;
    uint32_t d[4];
  } au;
  asm("v_cvt_pk_bf16_f32 %0, %1, %2" : "=v"(au.d[0]) : "v"(lo.x), "v"(lo.y));
  asm("v_cvt_pk_bf16_f32 %0, %1, %2" : "=v"(au.d[1]) : "v"(lo.z), "v"(lo.w));
  asm("v_cvt_pk_bf16_f32 %0, %1, %2" : "=v"(au.d[2]) : "v"(hi.x), "v"(hi.y));
  asm("v_cvt_pk_bf16_f32 %0, %1, %2" : "=v"(au.d[3]) : "v"(hi.z), "v"(hi.w));
  return au.v;
}

// ---- Stage 2: GEMM --------------------------------------------------------
__global__ __launch_bounds__(512, 2) void gemm_kernel(
    const float* __restrict__ X, const unsigned short* __restrict__ Wb,
    const float* __restrict__ bias, float* __restrict__ Out) {
  extern __shared__ char smem[];

  const int tid = threadIdx.x;
  const int lane = tid & 63;
  const int wave = tid >> 6;  // 8 waves: 2m x 4n
  const int wm = wave >> 2;   // 0..1: 64 m-rows each
  const int wn = wave & 3;    // 0..3: 128 n-cols each
  const size_t m0 = (size_t)blockIdx.x * BM;

  // ---- staging address precompute (thread-constant) ----
  // A tile: 1024 slots of 16B (row = slot>>3, q = slot&7), 2 calls.
  //   LDS(row,q) holds X granule (q ^ ((row&3)<<1)) of the 32-f32 K-window.
  // W slab: 2048 slots (row = slot>>2, q = slot&3), 4 calls.
  //   LDS(row,q) holds W granule (q ^ (row&3)) of the 32-bf16 K-window.
  const char* pA[2];
#pragma unroll
  for (int c = 0; c < 2; ++c) {
    int slot = c * 512 + tid;
    int row = slot >> 3, q = slot & 7;
    int gcol = (q ^ ((row & 3) << 1)) * 4;  // f32 units
    pA[c] = (const char*)(X + (m0 + row) * K_DIM + gcol);
  }
  const char* pW[4];
#pragma unroll
  for (int c = 0; c < 4; ++c) {
    int slot = c * 512 + tid;
    int row = slot >> 2, q = slot & 3;
    int gcol = (q ^ (row & 3)) * 8;  // bf16 units
    pW[c] = (const char*)(Wb + (size_t)row * K_DIM + gcol);
  }
  const int ldsA_base = wave * 1024;  // + c*8192 (wave-uniform dest)
  const int ldsW_base = wave * 1024;

#define STAGE(p_)                                                        \
  {                                                                      \
    _Pragma("unroll") for (int c = 0; c < 2; ++c)                        \
        gload16(pA[c], smem + AOFF(p_) + c * 8192 + ldsA_base);          \
    _Pragma("unroll") for (int c = 0; c < 4; ++c)                        \
        gload16(pW[c], smem + WOFF(p_) + c * 8192 + ldsW_base);          \
  }
// K-step advance: A rows are f32 (32*4=128 B), W rows are bf16 (32*2=64 B).
#define ADVANCE()                                                        \
  {                                                                      \
    _Pragma("unroll") for (int c = 0; c < 2; ++c) pA[c] += 128;          \
    _Pragma("unroll") for (int c = 0; c < 4; ++c) pW[c] += 64;           \
  }

  // ---- fragment-read LDS offsets (thread-constant, exclude buffer base) ----
  const int r = lane & 15;
  const int g = lane >> 4;
  int offA[4];  // x-frag i: row = wm*64+i*16+r, granule pair (2g)^((r&3)<<1)
#pragma unroll
  for (int i = 0; i < 4; ++i) {
    int row = wm * 64 + i * 16 + r;
    offA[i] = row * 128 + ((2 * g) ^ ((r & 3) << 1)) * 16;
  }
  int offW[8];  // w-frag j: row = wn*128+j*16+r, granule g^(r&3)
#pragma unroll
  for (int j = 0; j < 8; ++j) {
    int row = wn * 128 + j * 16 + r;
    offW[j] = row * 64 + (g ^ (r & 3)) * 16;
  }

  f32x4 acc[4][8];
#pragma unroll
  for (int i = 0; i < 4; ++i)
#pragma unroll
    for (int j = 0; j < 8; ++j) acc[i][j] = (f32x4){0.f, 0.f, 0.f, 0.f};

  // prologue: stage tile 0 into buffers 0
  STAGE(0)
  __syncthreads();  // implicit vmcnt(0) drain -> tile 0 ready

#pragma unroll
  for (int kt = 0; kt < NKT; ++kt) {
    if (kt < NKT - 1) {
      ADVANCE()
      STAGE((kt + 1) & 1)  // in flight during this step's compute
    }

    // compute tile kt from buffers kt&1
    bf16x8 xa[4];
#pragma unroll
    for (int i = 0; i < 4; ++i) {
      const char* a = smem + AOFF(kt & 1) + offA[i];
      float4 lo = *reinterpret_cast<const float4*>(a);
      float4 hi = *reinterpret_cast<const float4*>(a + 16);
      xa[i] = cvt8(lo, hi);
    }
#pragma unroll
    for (int j = 0; j < 8; ++j) {
      bf16x8 wb = *reinterpret_cast<const bf16x8*>(smem + WOFF(kt & 1) + offW[j]);
#pragma unroll
      for (int i = 0; i < 4; ++i)
        acc[i][j] = __builtin_amdgcn_mfma_f32_16x16x32_bf16(wb, xa[i],
                                                            acc[i][j], 0, 0, 0);
    }

    if (kt < NKT - 1)
      __syncthreads();  // read-done for buf kt&1 + drains stage(kt+1)
  }

  // ---- epilogue. Swapped operands: D.col(lane&15)=x-row, D.row(quads)=out-col
  // acc[i][j][q] -> Out[m0 + wm*64 + i*16 + r][wn*128 + j*16 + g*4 + q]
#pragma unroll
  for (int i = 0; i < 4; ++i) {
    const size_t rowoff = (m0 + wm * 64 + i * 16 + r) * N_DIM;
#pragma unroll
    for (int j = 0; j < 8; ++j) {
      const int c0 = wn * 128 + j * 16 + g * 4;
      float4 bv = *reinterpret_cast<const float4*>(&bias[c0]);
      float4 o;
      o.x = acc[i][j][0] + bv.x;
      o.y = acc[i][j][1] + bv.y;
      o.z = acc[i][j][2] + bv.z;
      o.w = acc[i][j][3] + bv.w;
      *reinterpret_cast<float4*>(&Out[rowoff + c0]) = o;
    }
  }
#undef STAGE
#undef ADVANCE
}

extern "C" void kernel_launch(void* const* d_in, const int* in_sizes, int n_in,
                              void* d_out, int out_size, void* d_ws,
                              size_t ws_size, hipStream_t stream) {
  (void)in_sizes;
  (void)n_in;
  (void)out_size;
  (void)ws_size;
  const float* x = (const float*)d_in[0];
  const float* alpha = (const float*)d_in[1];
  const float* U = (const float*)d_in[2];
  const float* V = (const float*)d_in[3];
  const float* bias = (const float*)d_in[4];
  const int* k_iter = (const int*)d_in[5];
  float* out = (float*)d_out;
  unsigned short* Wb = (unsigned short*)d_ws;  // 512 KiB scratch

  build_w_kernel<<<(N_DIM * K_DIM) / 256, 256, 0, stream>>>(alpha, U, V,
                                                            k_iter, Wb);

  const int lds_bytes = 98304;  // A 2x16KB + W 2x32KB
  hipFuncSetAttribute((const void*)gemm_kernel,
                      hipFuncAttributeMaxDynamicSharedMemorySize, lds_bytes);
  const int grid = M_TOTAL / BM;  // 1024 blocks, each covers all 512 cols
  gemm_kernel<<<grid, 512, lds_bytes, stream>>>(x, Wb, bias, out);
}